// Round 9
// baseline (418.427 us; speedup 1.0000x reference)
//
#include <hip/hip_runtime.h>

#define V 128
#define D 20
#define NUM_EMB (V * V * V)
#define NBUCK 32768       // 32^3 coarse blocks of 4^3 cells
#define BCAP  38          // slots/bucket; mean 30.5 -> 3 consume slots of 64
#define OVFCAP 32768      // Poisson tail (~11k pts expected) handled correctly
#define NBLK  2048        // persistent gather blocks (8/CU, 1 wave each)
#define BPB   (NBUCK / NBLK)   // 16 buckets per block
#define SLABF 2560        // floats per slab (10 stage-insts x 256)

typedef float v4f __attribute__((ext_vector_type(4)));
typedef unsigned int u32;

// Direct-to-LDS: per-lane GLOBAL src, LDS dest = wave-uniform base + lane*16.
typedef const __attribute__((address_space(1))) void gv_t;
typedef __attribute__((address_space(3))) void lv_t;
#define G2L(gsrc, ldst) \
    __builtin_amdgcn_global_load_lds((gv_t*)(gsrc), (lv_t*)(ldst), 16, 0, 0)

// ---- per-(point,chunk) direct-from-global compute (R0-verified body). ----
__device__ __forceinline__ void compute_chunk(
    const float* __restrict__ x, const float* __restrict__ grid,
    float* __restrict__ out, int i, int k)
{
    float px = x[3 * i + 0];
    float py = x[3 * i + 1];
    float pz = x[3 * i + 2];
    int ix = (int)floorf((px + 1.0f) * 64.0f);
    int iy = (int)floorf((py + 1.0f) * 64.0f);
    int iz = (int)floorf((pz + 1.0f) * 64.0f);

    float x1 = (float)ix * (2.0f / 128.0f) - 1.0f;
    float x2 = (float)(ix + 1) * (2.0f / 128.0f) - 1.0f;
    float y1 = (float)iy * (2.0f / 128.0f) - 1.0f;
    float y2 = (float)(iy + 1) * (2.0f / 128.0f) - 1.0f;
    float z1 = (float)iz * (2.0f / 128.0f) - 1.0f;
    float z2 = (float)(iz + 1) * (2.0f / 128.0f) - 1.0f;

    float wx1 = (px - x1) * 64.0f, wx0 = (x2 - px) * 64.0f;
    float wy1 = (py - y1) * 64.0f, wy0 = (y2 - py) * 64.0f;
    float wz1 = (pz - z1) * 64.0f, wz0 = (z2 - pz) * 64.0f;

    int f000 = ix + iy * V + iz * V * V;
    int flats[8] = { f000,             f000 + 1,
                     f000 + V,         f000 + V + 1,
                     f000 + V * V,     f000 + V * V + 1,
                     f000 + V * V + V, f000 + V * V + V + 1 };
    #pragma unroll
    for (int c = 0; c < 8; c++)
        if (flats[c] > NUM_EMB - 1) flats[c] = NUM_EMB - 1;

    float w[8];
    w[0] = wx0 * wy0 * wz0; w[1] = wx1 * wy0 * wz0;
    w[2] = wx0 * wy1 * wz0; w[3] = wx1 * wy1 * wz0;
    w[4] = wx0 * wy0 * wz1; w[5] = wx1 * wy0 * wz1;
    w[6] = wx0 * wy1 * wz1; w[7] = wx1 * wy1 * wz1;

    v4f q[8];
    #pragma unroll
    for (int c = 0; c < 8; c++)
        q[c] = *(const v4f*)(grid + (size_t)flats[c] * D + 4 * k);

    v4f acc = (v4f)(0.0f);
    #pragma unroll
    for (int c = 0; c < 8; c++) acc += w[c] * q[c];

    __builtin_nontemporal_store(acc, (v4f*)(out + (size_t)i * D + 4 * k));
}

// ---- pass 1: bin points by 4^3-cell block (R8-verified logic) -------------
__global__ __launch_bounds__(256) void bin_kernel(
    const float* __restrict__ x, const float* __restrict__ grid,
    float* __restrict__ out, u32* __restrict__ cnt, u32* __restrict__ blist,
    u32* __restrict__ ovfc, u32* __restrict__ ovf, int N)
{
    int i = blockIdx.x * 256 + threadIdx.x;
    if (i >= N) return;
    float px = x[3 * i + 0];
    float py = x[3 * i + 1];
    float pz = x[3 * i + 2];
    int ix = (int)floorf((px + 1.0f) * 64.0f);
    int iy = (int)floorf((py + 1.0f) * 64.0f);
    int iz = (int)floorf((pz + 1.0f) * 64.0f);
    int b = (ix >> 2) + ((iy >> 2) << 5) + ((iz >> 2) << 10);
    u32 pos = atomicAdd(&cnt[b], 1u);
    if (pos < BCAP) {
        blist[(size_t)b * BCAP + pos] = (u32)i;
    } else {
        u32 op = atomicAdd(ovfc, 1u);
        if (op < OVFCAP) ovf[op] = (u32)i;
        else for (int k = 0; k < 5; k++) compute_chunk(x, grid, out, i, k);
    }
}

// ---- consume one point-slot from the LDS slab (R8-verified math) -----------
__device__ __forceinline__ void emit_point(
    const float* slab, int gx0, int gy0, int gz0,
    float px, float py, float pz, int i, int k, float* __restrict__ out)
{
    float gxf = (px + 1.0f) * 64.0f;
    float gyf = (py + 1.0f) * 64.0f;
    float gzf = (pz + 1.0f) * 64.0f;
    float ixf = floorf(gxf), iyf = floorf(gyf), izf = floorf(gzf);
    float fx = gxf - ixf;   // == (px-x1)*64 (verified numerics)
    float fy = gyf - iyf;
    float fz = gzf - izf;
    int lx = (int)ixf - gx0;    // 0..3 by construction of the binning
    int ly = (int)iyf - gy0;
    int lz = (int)izf - gz0;
    int l000 = (lz * 5 + ly) * 5 + lx;

    v4f acc = (v4f)(0.0f);
    #pragma unroll
    for (int c = 0; c < 8; c++) {
        int l = l000 + (c & 1) + ((c >> 1) & 1) * 5 + ((c >> 2) & 1) * 25;
        v4f q = *(const v4f*)(slab + l * 20 + k * 4);
        float wgt = ((c & 1)        ? fx : 1.0f - fx)
                  * (((c >> 1) & 1) ? fy : 1.0f - fy)
                  * (((c >> 2) & 1) ? fz : 1.0f - fz);
        acc += wgt * q;
    }
    __builtin_nontemporal_store(acc, (v4f*)(out + (size_t)i * D + k * 4));
}

// ---- pass 2: persistent 1-wave blocks, 16 buckets each, double-buffered
// LDS slabs. Counted vmcnt(10) keeps the NEXT bucket's 10 global_load_lds in
// flight across the consume phase (loads retire in order: <=10 outstanding
// means everything older -- i.e. the CURRENT slab -- has landed). No
// __syncthreads anywhere: the vmcnt(0)+barrier drain that pinned R7/R8 at
// 139us is gone. Prep loads (blist/x) are issued BEFORE the next stage so
// compiler-inserted waits for them count the younger G2Ls, not drain them. --
__global__ __launch_bounds__(64) void gather_kernel(
    const float* __restrict__ x, const float* __restrict__ grid,
    float* __restrict__ out, const u32* __restrict__ cnt,
    const u32* __restrict__ blist)
{
    __shared__ __align__(16) float reg[2][SLABF];

    const int lane = threadIdx.x;
    // XCD-chunked bijective swizzle (2048 % 8 == 0): each XCD owns a
    // contiguous z-slab of buckets -> overlap planes stay in its L2.
    int j  = blockIdx.x;
    int jp = (j & 7) * (NBLK / 8) + (j >> 3);
    const int b0 = jp * BPB;

    // Per-lane staging constants (region-relative flat offset + chunk byte).
    int rel[10], cb[10];
    #pragma unroll
    for (int w = 0; w < 10; ++w) {
        int t = w * 64 + lane;
        if (t > 624) t = 624;            // src clamp; dest = slab pad
        int row = t / 5;
        int c   = t - row * 5;
        int sx = row % 5;
        int r5 = row / 5;
        int sy = r5 % 5;
        int sz = r5 / 5;
        rel[w] = sx + sy * V + sz * (V * V);
        cb[w]  = c * 16;
    }
    // Consume slot constants (3 slots of 64 tasks cover BCAP*5 = 190).
    const int p0 = lane / 5,         k0 = lane - 5 * p0;
    const int p1 = (lane + 64) / 5,  k1 = (lane + 64) - 5 * p1;
    const int p2 = (lane + 128) / 5, k2 = (lane + 128) - 5 * p2;

    // Prologue: stage bucket b0 into slab 0.
    {
        int b = b0;
        int fb = ((b & 31) << 2) + (((b >> 5) & 31) << 2) * V
               + ((b >> 10) << 2) * (V * V);
        #pragma unroll
        for (int w = 0; w < 10; ++w) {
            int flat = fb + rel[w];
            if (flat > NUM_EMB - 1) flat = NUM_EMB - 1;  // JAX OOB clamp
            G2L((const char*)grid + (size_t)flat * 80 + cb[w],
                &reg[0][0] + w * 256);
        }
    }

    for (int t = 0; t < BPB; ++t) {
        const float* cur = &reg[0][0] + ((t & 1) ? SLABF : 0);
        float*       nxt = &reg[0][0] + ((t & 1) ? 0 : SLABF);

        int b = b0 + t;
        int gx0 = (b & 31) << 2, gy0 = ((b >> 5) & 31) << 2, gz0 = (b >> 10) << 2;

        // ---- prep: issue current bucket's blist/x loads (oldest in queue)
        u32 n = cnt[b]; if (n > BCAP) n = BCAP;
        int total = (int)n * 5;
        bool v0 = lane < total, v1 = lane + 64 < total, v2 = lane + 128 < total;
        int i0 = 0, i1 = 0, i2 = 0;
        float px0 = 0, py0 = 0, pz0 = 0, px1 = 0, py1 = 0, pz1 = 0,
              px2 = 0, py2 = 0, pz2 = 0;
        if (v0) { i0 = (int)blist[(size_t)b * BCAP + p0];
                  px0 = x[3*i0]; py0 = x[3*i0+1]; pz0 = x[3*i0+2]; }
        if (v1) { i1 = (int)blist[(size_t)b * BCAP + p1];
                  px1 = x[3*i1]; py1 = x[3*i1+1]; pz1 = x[3*i1+2]; }
        if (v2) { i2 = (int)blist[(size_t)b * BCAP + p2];
                  px2 = x[3*i2]; py2 = x[3*i2+1]; pz2 = x[3*i2+2]; }
        __builtin_amdgcn_sched_barrier(0);

        // ---- stage NEXT bucket into the other slab (stays in flight)
        if (t + 1 < BPB) {
            int bn = b + 1;
            int fb = ((bn & 31) << 2) + (((bn >> 5) & 31) << 2) * V
                   + ((bn >> 10) << 2) * (V * V);
            #pragma unroll
            for (int w = 0; w < 10; ++w) {
                int flat = fb + rel[w];
                if (flat > NUM_EMB - 1) flat = NUM_EMB - 1;
                G2L((const char*)grid + (size_t)flat * 80 + cb[w], nxt + w * 256);
            }
            // <=10 outstanding: the 10 youngest are exactly the G2Ls above
            // (in-order retirement) -> cur slab complete, next still flying.
            __builtin_amdgcn_s_waitcnt(0x0F7A);   // vmcnt(10)
        } else {
            __builtin_amdgcn_s_waitcnt(0x0F70);   // vmcnt(0) epilogue
        }
        __builtin_amdgcn_sched_barrier(0);        // rule 18: pin ds_reads below

        // ---- consume current bucket from LDS
        if (v0) emit_point(cur, gx0, gy0, gz0, px0, py0, pz0, i0, k0, out);
        if (v1) emit_point(cur, gx0, gy0, gz0, px1, py1, pz1, i1, k1, out);
        if (v2) emit_point(cur, gx0, gy0, gz0, px2, py2, pz2, i2, k2, out);
    }
}

// ---- pass 3: drain the overflow list (~1% of points at BCAP=38) ------------
__global__ __launch_bounds__(256) void ovf_kernel(
    const float* __restrict__ x, const float* __restrict__ grid,
    float* __restrict__ out, const u32* __restrict__ ovfc,
    const u32* __restrict__ ovf)
{
    u32 n = *ovfc;
    if (n > OVFCAP) n = OVFCAP;
    int total = (int)n * 5;
    for (int u = blockIdx.x * 256 + threadIdx.x; u < total;
         u += 256 * (int)gridDim.x) {
        int p = u / 5;
        int k = u - p * 5;
        compute_chunk(x, grid, out, (int)ovf[p], k);
    }
}

// ---- fallback: verified round-0 kernel (used only if ws too small) ---------
__global__ __launch_bounds__(320) void naive_kernel(
    const float* __restrict__ x, const float* __restrict__ grid,
    float* __restrict__ out, int N)
{
    int tid = threadIdx.x;
    int lp  = tid / 5;
    int k   = tid - lp * 5;
    int i   = blockIdx.x * 64 + lp;
    if (i >= N) return;
    compute_chunk(x, grid, out, i, k);
}

extern "C" void kernel_launch(void* const* d_in, const int* in_sizes, int n_in,
                              void* d_out, int out_size, void* d_ws, size_t ws_size,
                              hipStream_t stream) {
    const float* x = (const float*)d_in[0];
    const float* grid = (const float*)d_in[1];
    float* out = (float*)d_out;
    int N = in_sizes[0] / 3;

    // ws: [cnt 32768][ovfc 1][ovf 32768][blist 32768*38] u32 = ~5.25 MB
    size_t need = ((size_t)NBUCK + 1 + OVFCAP + (size_t)NBUCK * BCAP) * 4;
    if (d_ws == nullptr || ws_size < need) {
        int nblocks = (N + 63) / 64;
        naive_kernel<<<nblocks, 320, 0, stream>>>(x, grid, out, N);
        return;
    }

    u32* cnt   = (u32*)d_ws;
    u32* ovfc  = cnt + NBUCK;
    u32* ovf   = ovfc + 1;
    u32* blist = ovf + OVFCAP;

    hipMemsetAsync(cnt, 0, (size_t)(NBUCK + 1) * 4, stream);  // cnt + ovfc
    bin_kernel<<<(N + 255) / 256, 256, 0, stream>>>(
        x, grid, out, cnt, blist, ovfc, ovf, N);
    gather_kernel<<<NBLK, 64, 0, stream>>>(x, grid, out, cnt, blist);
    ovf_kernel<<<64, 256, 0, stream>>>(x, grid, out, ovfc, ovf);
}